// Round 13
// baseline (850.179 us; speedup 1.0000x reference)
//
#include <hip/hip_runtime.h>
#include <hip/hip_bf16.h>

// ---------------- workspace layout ----------------
// [0)        u32 cnt[16384]           per-(batch,zbin) pair counts
// [65536)    u32 ovf_cnt              overflow pair count
// [65792)    uint2 ovf[65536]         overflow pairs (global_cell, label)
// [1MB)      uint2 pairs[nb][C]       per-bin pair lists, C from ws_size
#define CNT_MAX   16384
#define OVF_OFF   65792
#define OVF_CAP   65536
#define PAIRS_OFF (1u << 20)
#define BIN_ROWS  8          // 8 BEV rows per z-bin -> 32KB LDS tile @ w=1024

__device__ __forceinline__ int pairs_cap(size_t ws_size, int nb) {
    long long c = (long long)((ws_size - PAIRS_OFF) / (8ull * (unsigned long long)nb));
    return (int)(c > 0x7fffffff ? 0x7fffffff : c);
}

// K0: zero counters + overflow counter (re-run every call; ws not re-poisoned).
__global__ void bev_zero_kernel(unsigned* __restrict__ ws) {
    int i = blockIdx.x * blockDim.x + threadIdx.x;
    if (i < CNT_MAX + 64) ws[i] = 0u;   // cnt[16384] + ovf_cnt + pad
}

// K1: compute class-E indices (verified R11) and append (local_cell,label)
// pairs to per-(batch,zbin) lists. Class E: single f32 rounding of the EXACT
// quotient a/(0.1*scale) == f32((f64)a * rd), rd = f64 1/(0.1*scale) (== 10.0
// exactly for scale=1). rd asm-opaqued so no pass narrows the f64 chain to a
// f32 multiply. Then f32 add 512.0f, rintf (RNE), trunc, bounds-drop.
__global__ void bev_pair_kernel(const float* __restrict__ labels,
                                const float* __restrict__ pc,
                                const int* __restrict__ p_bev_h,
                                const int* __restrict__ p_bev_w,
                                const int* __restrict__ p_scale,
                                unsigned* __restrict__ ws,
                                int n_pts, int out_size, size_t ws_size) {
    const int bev_h = *p_bev_h;
    const int bev_w = *p_bev_w;
    const int scale = *p_scale;
    const double res_d = 0.1 * (double)scale;
    const float half_w = (float)(bev_w / 2);
    double rd = 1.0 / res_d;
    asm volatile("" : "+v"(rd));

    const int img = bev_h * bev_w;
    const int B = out_size / img;
    const int HW = n_pts / B;
    const int nbins = (bev_h + BIN_ROWS - 1) / BIN_ROWS;
    const int nb = B * nbins;
    const int C = pairs_cap(ws_size, nb);

    unsigned* cnt = ws;
    unsigned* ovf_cnt = ws + CNT_MAX;
    uint2* ovf = (uint2*)((char*)ws + OVF_OFF);
    uint2* pairs = (uint2*)((char*)ws + PAIRS_OFF);

    int t = blockIdx.x * blockDim.x + threadIdx.x;
    int i4 = t * 4;
    if (i4 >= n_pts) return;
    int b = i4 / HW;
    int r = i4 - b * HW;

    const float* pcb = pc + (size_t)b * 3u * (size_t)HW;
    float4 lab = *(const float4*)(labels + (size_t)b * (size_t)HW + r);
    float4 x0  = *(const float4*)(pcb + r);
    float4 z0  = *(const float4*)(pcb + 2 * (size_t)HW + r);

    float xs[4] = {x0.x, x0.y, x0.z, x0.w};
    float zs[4] = {z0.x, z0.y, z0.z, z0.w};
    float ls[4] = {lab.x, lab.y, lab.z, lab.w};

#pragma unroll
    for (int k = 0; k < 4; ++k) {
        float xq = (float)((double)(-xs[k]) * rd);   // class-E quotient
        float zq = (float)((double)zs[k] * rd);
        float xf = rintf(__fadd_rn(xq, half_w));
        float zf = rintf(zq);
        int xi = (int)xf;
        int zi = (int)zf;
        if (xi >= 0 && xi < bev_w && zi >= 0 && zi < bev_h) {
            int bin = b * nbins + (zi >> 3);
            unsigned pos = atomicAdd(&cnt[bin], 1u);
            if ((int)pos < C) {
                pairs[(size_t)bin * (size_t)C + pos] =
                    make_uint2((unsigned)((zi & 7) * bev_w + xi),
                               __float_as_uint(ls[k]));
            } else {
                unsigned op = atomicAdd(ovf_cnt, 1u);
                if (op < OVF_CAP)
                    ovf[op] = make_uint2(
                        (unsigned)((size_t)b * img + (size_t)zi * bev_w + xi),
                        __float_as_uint(ls[k]));
            }
        }
    }
}

// K2: one workgroup per (batch, zbin): LDS tile init to EMPTY, scatter the
// bin's pairs into LDS (no global scattered stores!), stream tile out
// coalesced. Replaces the fill pass entirely.
__global__ __launch_bounds__(256) void bev_tile_kernel(
        const int* __restrict__ p_bev_h, const int* __restrict__ p_bev_w,
        unsigned* __restrict__ ws, float* __restrict__ out,
        int out_size, size_t ws_size) {
    __shared__ float tile[BIN_ROWS * 1024];   // 32 KB; requires bev_w <= 1024
    const int bev_h = *p_bev_h;
    const int bev_w = *p_bev_w;
    const int img = bev_h * bev_w;
    const int B = out_size / img;
    const int nbins = (bev_h + BIN_ROWS - 1) / BIN_ROWS;
    const int ntiles = B * nbins;
    const int C = pairs_cap(ws_size, ntiles);
    if (bev_w > 1024) return;                 // shape guard (never true here)

    unsigned* cnt = ws;
    const uint2* pairs = (const uint2*)((const char*)ws + PAIRS_OFF);

    for (int t = blockIdx.x; t < ntiles; t += gridDim.x) {
        int b = t / nbins;
        int bin = t - b * nbins;
        int nrows = min(BIN_ROWS, bev_h - bin * BIN_ROWS);
        int nel = nrows * bev_w;

        for (int i = threadIdx.x; i < nel; i += blockDim.x) tile[i] = 255.0f;
        __syncthreads();

        int count = min((int)cnt[t], C);
        const uint2* pb = pairs + (size_t)t * (size_t)C;
        for (int i = threadIdx.x; i < count; i += blockDim.x) {
            uint2 p = pb[i];
            tile[p.x] = __uint_as_float(p.y);   // LDS scatter, races OK
        }
        __syncthreads();

        float4* dst = (float4*)(out + (size_t)b * img +
                                (size_t)bin * BIN_ROWS * bev_w);
        const float4* src = (const float4*)tile;
        int n4 = nel >> 2;
        for (int i = threadIdx.x; i < n4; i += blockDim.x) dst[i] = src[i];
        __syncthreads();
    }
}

// K3: scatter the (rare) overflow pairs directly; runs after K2 so they win.
__global__ void bev_ovf_kernel(const unsigned* __restrict__ ws,
                               float* __restrict__ out) {
    unsigned n = ws[CNT_MAX];
    if (n > OVF_CAP) n = OVF_CAP;
    const uint2* ovf = (const uint2*)((const char*)ws + OVF_OFF);
    for (unsigned i = blockIdx.x * blockDim.x + threadIdx.x; i < n;
         i += gridDim.x * blockDim.x) {
        uint2 p = ovf[i];
        out[p.x] = __uint_as_float(p.y);
    }
}

// ---------------- fallback path (R12, ws too small) ----------------
__global__ void bev_fill_kernel(float4* __restrict__ out, int n4) {
    int idx = blockIdx.x * blockDim.x + threadIdx.x;
    int stride = gridDim.x * blockDim.x;
    const float4 v = make_float4(255.0f, 255.0f, 255.0f, 255.0f);
    for (int i = idx; i < n4; i += stride) out[i] = v;
}

__global__ void bev_scatter_kernel(const float* __restrict__ labels,
                                   const float* __restrict__ pc,
                                   const int* __restrict__ p_bev_h,
                                   const int* __restrict__ p_bev_w,
                                   const int* __restrict__ p_scale,
                                   float* __restrict__ out,
                                   int n_pts, int out_size) {
    const int bev_h = *p_bev_h;
    const int bev_w = *p_bev_w;
    const int scale = *p_scale;
    const double res_d = 0.1 * (double)scale;
    const float half_w = (float)(bev_w / 2);
    double rd = 1.0 / res_d;
    asm volatile("" : "+v"(rd));

    const int img = bev_h * bev_w;
    const int B = out_size / img;
    const int HW = n_pts / B;

    int t = blockIdx.x * blockDim.x + threadIdx.x;
    int i4 = t * 4;
    if (i4 >= n_pts) return;
    int b = i4 / HW;
    int r = i4 - b * HW;

    const float* pcb = pc + (size_t)b * 3u * (size_t)HW;
    float4 lab = *(const float4*)(labels + (size_t)b * (size_t)HW + r);
    float4 x0  = *(const float4*)(pcb + r);
    float4 z0  = *(const float4*)(pcb + 2 * (size_t)HW + r);
    float* outb = out + (size_t)b * (size_t)img;

    float xs[4] = {x0.x, x0.y, x0.z, x0.w};
    float zs[4] = {z0.x, z0.y, z0.z, z0.w};
    float ls[4] = {lab.x, lab.y, lab.z, lab.w};

#pragma unroll
    for (int k = 0; k < 4; ++k) {
        float xq = (float)((double)(-xs[k]) * rd);
        float zq = (float)((double)zs[k] * rd);
        float xf = rintf(__fadd_rn(xq, half_w));
        float zf = rintf(zq);
        int xi = (int)xf;
        int zi = (int)zf;
        if (xi >= 0 && xi < bev_w && zi >= 0 && zi < bev_h)
            outb[(size_t)zi * (size_t)bev_w + (size_t)xi] = ls[k];
    }
}

extern "C" void kernel_launch(void* const* d_in, const int* in_sizes, int n_in,
                              void* d_out, int out_size, void* d_ws, size_t ws_size,
                              hipStream_t stream) {
    const float* labels = (const float*)d_in[0];
    const float* pc     = (const float*)d_in[1];
    const int* p_bev_h  = (const int*)d_in[2];
    const int* p_bev_w  = (const int*)d_in[3];
    const int* p_scale  = (const int*)d_in[4];
    float* out = (float*)d_out;
    int n_pts = in_sizes[0];

    if (ws_size >= (32u << 20)) {
        unsigned* ws = (unsigned*)d_ws;
        // K0: zero counters
        bev_zero_kernel<<<(CNT_MAX + 64 + 255) / 256, 256, 0, stream>>>(ws);
        // K1: pair append
        int n_thr = (n_pts + 3) / 4;
        bev_pair_kernel<<<(n_thr + 255) / 256, 256, 0, stream>>>(
            labels, pc, p_bev_h, p_bev_w, p_scale, ws, n_pts, out_size, ws_size);
        // K2: tile assemble + write (also does the EMPTY fill)
        bev_tile_kernel<<<2048, 256, 0, stream>>>(p_bev_h, p_bev_w, ws, out,
                                                  out_size, ws_size);
        // K3: overflow scatter
        bev_ovf_kernel<<<64, 256, 0, stream>>>(ws, out);
    } else {
        // fallback: fill + direct scatter
        int n4 = out_size / 4;
        bev_fill_kernel<<<2048, 256, 0, stream>>>((float4*)out, n4);
        int n_thr = (n_pts + 3) / 4;
        bev_scatter_kernel<<<(n_thr + 255) / 256, 256, 0, stream>>>(
            labels, pc, p_bev_h, p_bev_w, p_scale, out, n_pts, out_size);
    }
}

// Round 15
// 101.729 us; speedup vs baseline: 8.3573x; 8.3573x over previous
//
#include <hip/hip_runtime.h>
#include <hip/hip_bf16.h>

typedef float v4f __attribute__((ext_vector_type(4)));   // native clang vector

// Map physical block -> (batch, chunk) with XCD affinity (kept from R12;
// harmless, and keeps whatever L2/L3 locality remains useful).
__device__ __forceinline__ void map_block(int j, int B, int bpb,
                                          int& batch, int& chunk) {
    if ((B & 7) == 0) {
        int xcd = j & 7;
        int g = j >> 3;
        int per = B >> 3;
        batch = xcd + 8 * (g % per);
        chunk = g / per;
    } else {
        batch = j / bpb;
        chunk = j - batch * bpb;
    }
}

// Fill the BEV output with EMPTY (255.0f) using NON-TEMPORAL 16B stores:
// no L2 write-allocate, stream out. nt policy matches the scatter kernel.
__global__ void bev_fill_kernel(v4f* __restrict__ out,
                                const int* __restrict__ p_bev_h,
                                const int* __restrict__ p_bev_w,
                                int out_size) {
    const int img  = (*p_bev_h) * (*p_bev_w);
    const int img4 = img >> 2;
    const int B    = out_size / img;
    const int bpb  = (img4 + 1023) >> 10;

    int batch, chunk;
    map_block(blockIdx.x, B, bpb, batch, chunk);
    if (batch >= B) return;

    v4f* dst = out + (size_t)batch * (size_t)img4;
    int base = (chunk << 10) + threadIdx.x;
    const v4f v = {255.0f, 255.0f, 255.0f, 255.0f};
#pragma unroll
    for (int k = 0; k < 4; ++k) {
        int idx = base + (k << 8);
        if (idx < img4) __builtin_nontemporal_store(v, &dst[idx]);
    }
}

// Scatter labels into BEV with NON-TEMPORAL 4B stores: bypass the L2
// write-allocate RMW (fetch 64B line, modify 4B, evict) that made the direct
// scatter latency-bound. Index math = class E (verified R11): single f32
// rounding of the EXACT quotient a/(0.1*scale) == f32((f64)a * rd),
// rd = f64 1/(0.1*scale) (== 10.0 exactly for scale=1), asm-opaqued so no
// pass narrows the f64 chain to an f32 multiply. Then f32 add 512.0f,
// rintf (RNE), trunc-to-int, drop OOB, racy last-writer-wins scatter.
__global__ void bev_scatter_kernel(const float* __restrict__ labels,
                                   const float* __restrict__ pc,
                                   const int* __restrict__ p_bev_h,
                                   const int* __restrict__ p_bev_w,
                                   const int* __restrict__ p_scale,
                                   float* __restrict__ out,
                                   int n_pts, int out_size) {
    const int bev_h = *p_bev_h;
    const int bev_w = *p_bev_w;
    const int scale = *p_scale;
    const double res_d = 0.1 * (double)scale;
    const float half_w = (float)(bev_w / 2);

    double rd = 1.0 / res_d;
    asm volatile("" : "+v"(rd));

    const int img = bev_h * bev_w;
    const int B = out_size / img;
    const int HW = n_pts / B;
    const int bpb = (HW + 1023) >> 10;

    int batch, chunk;
    map_block(blockIdx.x, B, bpb, batch, chunk);
    if (batch >= B) return;

    int r = ((chunk << 8) + threadIdx.x) << 2;
    if (r >= HW) return;

    const float* pcb = pc + (size_t)batch * 3u * (size_t)HW;
    float4 lab = *(const float4*)(labels + (size_t)batch * (size_t)HW + r);
    float4 x0  = *(const float4*)(pcb + r);
    float4 z0  = *(const float4*)(pcb + 2 * (size_t)HW + r);

    float* outb = out + (size_t)batch * (size_t)img;

    float xs[4] = {x0.x, x0.y, x0.z, x0.w};
    float zs[4] = {z0.x, z0.y, z0.z, z0.w};
    float ls[4] = {lab.x, lab.y, lab.z, lab.w};

#pragma unroll
    for (int k = 0; k < 4; ++k) {
        float xq = (float)((double)(-xs[k]) * rd);   // class-E quotient
        float zq = (float)((double)zs[k] * rd);
        float xf = rintf(__fadd_rn(xq, half_w));
        float zf = rintf(zq);
        int xi = (int)xf;
        int zi = (int)zf;
        if (xi >= 0 && xi < bev_w && zi >= 0 && zi < bev_h) {
            __builtin_nontemporal_store(
                ls[k], &outb[(size_t)zi * (size_t)bev_w + (size_t)xi]);
        }
    }
}

extern "C" void kernel_launch(void* const* d_in, const int* in_sizes, int n_in,
                              void* d_out, int out_size, void* d_ws, size_t ws_size,
                              hipStream_t stream) {
    const float* labels = (const float*)d_in[0];   // (B,1,H,W) f32
    const float* pc     = (const float*)d_in[1];   // (B,3,H,W) f32
    const int* p_bev_h  = (const int*)d_in[2];
    const int* p_bev_w  = (const int*)d_in[3];
    const int* p_scale  = (const int*)d_in[4];
    float* out = (float*)d_out;

    int n_pts = in_sizes[0];

    // 1) fill with EMPTY (nt stores)
    int fill_blocks = (out_size + 4095) / 4096;
    bev_fill_kernel<<<fill_blocks, 256, 0, stream>>>((v4f*)out, p_bev_h,
                                                     p_bev_w, out_size);

    // 2) scatter (nt stores)
    int sc_blocks = (n_pts + 1023) / 1024;
    bev_scatter_kernel<<<sc_blocks, 256, 0, stream>>>(labels, pc, p_bev_h,
                                                      p_bev_w, p_scale, out,
                                                      n_pts, out_size);
}

// Round 16
// 43.380 us; speedup vs baseline: 19.5986x; 2.3451x over previous
//
#include <hip/hip_runtime.h>
#include <hip/hip_bf16.h>

typedef float v4f __attribute__((ext_vector_type(4)));

// Map physical block -> (batch, chunk) with XCD affinity.
__device__ __forceinline__ void map_block(int j, int B, int bpb,
                                          int& batch, int& chunk) {
    if ((B & 7) == 0) {
        int xcd = j & 7;
        int g = j >> 3;
        int per = B >> 3;
        batch = xcd + 8 * (g % per);
        chunk = g / per;
    } else {
        batch = j / bpb;
        chunk = j - batch * bpb;
    }
}

// Fill BEV with EMPTY (255.0f), non-temporal 16B stores (pure streaming
// write; keep the 67MB out of L2 so scatter RMW lines have the whole L2).
__global__ void bev_fill_kernel(v4f* __restrict__ out,
                                const int* __restrict__ p_bev_h,
                                const int* __restrict__ p_bev_w,
                                int out_size) {
    const int img  = (*p_bev_h) * (*p_bev_w);
    const int img4 = img >> 2;
    const int B    = out_size / img;
    const int bpb  = (img4 + 1023) >> 10;

    int batch, chunk;
    map_block(blockIdx.x, B, bpb, batch, chunk);
    if (batch >= B) return;

    v4f* dst = out + (size_t)batch * (size_t)img4;
    int base = (chunk << 10) + threadIdx.x;
    const v4f v = {255.0f, 255.0f, 255.0f, 255.0f};
#pragma unroll
    for (int k = 0; k < 4; ++k) {
        int idx = base + (k << 8);
        if (idx < img4) __builtin_nontemporal_store(v, &dst[idx]);
    }
}

// Scatter labels into BEV, REGULAR stores (L2 write-allocate merges the
// ~2 stores/line; nt was 2.3x worse, R15). 16 points per thread for deep
// store ILP: 16 independent stores issue back-to-back per lane before the
// wave drains vmcnt. Index math = class E (verified R11): single f32
// rounding of the EXACT quotient a/(0.1*scale) == f32((f64)a * rd),
// rd = f64 1/(0.1*scale), asm-opaqued; f32 add 512.0f, rintf (RNE),
// trunc-to-int, drop OOB, racy last-writer-wins.
__global__ void bev_scatter_kernel(const float* __restrict__ labels,
                                   const float* __restrict__ pc,
                                   const int* __restrict__ p_bev_h,
                                   const int* __restrict__ p_bev_w,
                                   const int* __restrict__ p_scale,
                                   float* __restrict__ out,
                                   int n_pts, int out_size) {
    const int bev_h = *p_bev_h;
    const int bev_w = *p_bev_w;
    const int scale = *p_scale;
    const double res_d = 0.1 * (double)scale;
    const float half_w = (float)(bev_w / 2);

    double rd = 1.0 / res_d;
    asm volatile("" : "+v"(rd));

    const int img = bev_h * bev_w;
    const int B = out_size / img;
    const int HW = n_pts / B;
    const int bpb = (HW + 4095) >> 12;          // 4096 points per block

    int batch, chunk;
    map_block(blockIdx.x, B, bpb, batch, chunk);
    if (batch >= B) return;

    int r0 = (chunk << 12) + (threadIdx.x << 2);   // first of 4x4 pts
    const float* pcb = pc + (size_t)batch * 3u * (size_t)HW;
    const float* labb = labels + (size_t)batch * (size_t)HW;
    float* outb = out + (size_t)batch * (size_t)img;

#pragma unroll
    for (int blk = 0; blk < 4; ++blk) {
        int r = r0 + (blk << 10);                  // stride 1024 between quads
        if (r >= HW) break;
        float4 lab = *(const float4*)(labb + r);
        float4 x0  = *(const float4*)(pcb + r);
        float4 z0  = *(const float4*)(pcb + 2 * (size_t)HW + r);

        float xs[4] = {x0.x, x0.y, x0.z, x0.w};
        float zs[4] = {z0.x, z0.y, z0.z, z0.w};
        float ls[4] = {lab.x, lab.y, lab.z, lab.w};

#pragma unroll
        for (int k = 0; k < 4; ++k) {
            float xq = (float)((double)(-xs[k]) * rd);   // class-E quotient
            float zq = (float)((double)zs[k] * rd);
            float xf = rintf(__fadd_rn(xq, half_w));
            float zf = rintf(zq);
            int xi = (int)xf;
            int zi = (int)zf;
            if (xi >= 0 && xi < bev_w && zi >= 0 && zi < bev_h)
                outb[(size_t)zi * (size_t)bev_w + (size_t)xi] = ls[k];
        }
    }
}

extern "C" void kernel_launch(void* const* d_in, const int* in_sizes, int n_in,
                              void* d_out, int out_size, void* d_ws, size_t ws_size,
                              hipStream_t stream) {
    const float* labels = (const float*)d_in[0];   // (B,1,H,W) f32
    const float* pc     = (const float*)d_in[1];   // (B,3,H,W) f32
    const int* p_bev_h  = (const int*)d_in[2];
    const int* p_bev_w  = (const int*)d_in[3];
    const int* p_scale  = (const int*)d_in[4];
    float* out = (float*)d_out;

    int n_pts = in_sizes[0];

    // 1) fill with EMPTY (nt streaming stores)
    int fill_blocks = (out_size + 4095) / 4096;
    bev_fill_kernel<<<fill_blocks, 256, 0, stream>>>((v4f*)out, p_bev_h,
                                                     p_bev_w, out_size);

    // 2) scatter (regular stores, 4096 pts/block)
    int sc_blocks = (n_pts + 4095) / 4096;
    bev_scatter_kernel<<<sc_blocks, 256, 0, stream>>>(labels, pc, p_bev_h,
                                                      p_bev_w, p_scale, out,
                                                      n_pts, out_size);
}